// Round 4
// baseline (142.062 us; speedup 1.0000x reference)
//
#include <hip/hip_runtime.h>
#include <hip/hip_bf16.h>

// SocialPooling round 4: dense MFMA scatter (P_g = S_g @ H), 3 dispatches.
// K0 sp_transpose: W -> Wt bf16 [g][col][k] (verified in R3).
// K1 sp_main: per-seq block; build u8 cellmap; per wave (owns 16 X-rows):
//   for each of 64 cells: S-frags from cellmap regs -> GEMM1 P=S@H (MFMA, f32 acc)
//   -> LDS roundtrip -> GEMM2 X += P@W_g (MFMA). No barriers in cell loop,
//   no atomics, no pair lists. Epilogue: X+bias write + column partial stats.
// K2 sp_finish: redundant-reduce partials -> scale/shift; normalize+ReLU in place.

#define NSEQ 256
#define NPED 64
#define HD   64
#define NTOT (NSEQ*NPED)
#define EPSV 1e-5f

typedef __attribute__((ext_vector_type(8))) short short8;
typedef __attribute__((ext_vector_type(4))) float f32x4;
typedef unsigned short ushort_t;

__device__ __forceinline__ ushort_t f2b(float f) {
    __hip_bfloat16 h = __float2bfloat16(f);                 // RNE
    return *reinterpret_cast<ushort_t*>(&h);
}

// ---------------- K0: transpose one W cell per block (verified R3) ----------------
__global__ __launch_bounds__(256) void sp_transpose(
    const float* __restrict__ W, short* __restrict__ Wt)
{
    __shared__ __align__(16) float Tl[64*68];
    const int b = blockIdx.x, tid = threadIdx.x;
    const float* wg = W + (size_t)b*4096;
    for (int m = 0; m < 4; ++m) {
        int c = m*256 + tid;
        int k = c >> 4, t0 = (c & 15)*4;
        *(f32x4*)(Tl + k*68 + t0) = *(const f32x4*)(wg + k*64 + t0);
    }
    __syncthreads();
    for (int m = 0; m < 2; ++m) {
        int q = m*256 + tid;
        int col = q >> 3, k0 = (q & 7)*8;
        short8 o;
        #pragma unroll
        for (int i2 = 0; i2 < 8; ++i2)
            o[i2] = (short)f2b(Tl[(k0 + i2)*68 + col]);
        *(short8*)(Wt + ((size_t)(b*64 + col)*64 + k0)) = o;  // Wt[g][col][k]
    }
}

// ---------------- K1: main ----------------
// LDS carve (bytes):
#define SM_HT   0        // u16 Ht[64][72]  (H transposed: Ht[kf][j])   9216
#define SM_PW   9216     // u16 Pw[64][72]  (P roundtrip, wave-disjoint rows) 9216
#define SM_CM   18432    // u8  cm[64][64]  cellmap                     4096
#define SM_POS  22528    // f32 px[64], py[64]                          512
#define SM_RED  23040    // f32 red1[4][64], red2[4][64]                2048
#define SM_TOT  25088

__global__ __launch_bounds__(256) void sp_main(
    const float* __restrict__ h, const float* __restrict__ pos,
    const short* __restrict__ Wt, const float* __restrict__ bvec,
    float* __restrict__ X, float* __restrict__ partials)
{
    __shared__ __align__(16) char smem[SM_TOT];
    ushort_t*      Ht   = (ushort_t*)(smem + SM_HT);
    ushort_t*      Pw   = (ushort_t*)(smem + SM_PW);
    unsigned char* cm   = (unsigned char*)(smem + SM_CM);
    float*         px   = (float*)(smem + SM_POS);
    float*         py   = px + 64;
    float*         red1 = (float*)(smem + SM_RED);          // [4][64]
    float*         red2 = red1 + 256;

    const int b    = blockIdx.x;            // sequence
    const int base = b * NPED;
    const int tid  = threadIdx.x;
    const int lane = tid & 63, w = tid >> 6;
    const int ln15 = lane & 15, ln4 = lane >> 4;

    if (tid < 64) { px[tid] = pos[(base + tid)*2]; py[tid] = pos[(base + tid)*2 + 1]; }
    // stage H transposed: Ht[kf][j] = bf16(H[j][kf])
    for (int m = 0; m < 4; ++m) {
        int c = m*256 + tid;
        int j = c >> 4, t0 = (c & 15)*4;
        f32x4 v = *(const f32x4*)(h + (size_t)(base + j)*64 + t0);
        #pragma unroll
        for (int u = 0; u < 4; ++u) Ht[(t0 + u)*72 + j] = f2b(v[u]);
    }
    __syncthreads();

    // cellmap: cm[i][j] = grid cell (0..63) if valid pair, else 255 (identical math to R1/R3)
    for (int m = 0; m < 16; ++m) {
        int p = m*256 + tid;
        int i = p >> 6, j = p & 63;
        unsigned char val = 255;
        if (i != j) {
            float ax = px[i], ay = py[i], ox = px[j], oy = py[j];
            float tlx = ax - 1.0f, tly = ay + 1.0f, brx = ax + 1.0f, bry = ay - 1.0f;
            bool oob = (ox >= brx) | (ox <= tlx) | (oy >= tly) | (oy <= bry);
            if (!oob) {
                int g = (int)(floorf((ox - tlx)*4.0f) + floorf((tly - oy)*4.0f)*8.0f);
                g = g < 0 ? 0 : (g > 63 ? 63 : g);
                val = (unsigned char)g;
            }
        }
        cm[i*64 + j] = val;
    }
    __syncthreads();

    // hoisted GEMM1 B-frags (H): B[k=j][n=kf], cell-independent
    short8 hf[2][4];
    #pragma unroll
    for (int kt = 0; kt < 2; ++kt)
        #pragma unroll
        for (int nt = 0; nt < 4; ++nt)
            hf[kt][nt] = *(const short8*)(Ht + (nt*16 + ln15)*72 + kt*32 + ln4*8);
    // hoisted cellmap bytes for this lane's S rows: i = w*16+ln15, j = kt*32+ln4*8+0..7
    unsigned cmv[2][2];
    #pragma unroll
    for (int kt = 0; kt < 2; ++kt) {
        const unsigned* cp = (const unsigned*)(cm + (w*16 + ln15)*64 + kt*32 + ln4*8);
        cmv[kt][0] = cp[0]; cmv[kt][1] = cp[1];
    }
    float bcol[4];
    #pragma unroll
    for (int nt = 0; nt < 4; ++nt) bcol[nt] = bvec[nt*16 + ln15];

    f32x4 acc[4];
    #pragma unroll
    for (int nt = 0; nt < 4; ++nt) acc[nt] = (f32x4){0.f,0.f,0.f,0.f};

    for (int g = 0; g < 64; ++g) {
        // GEMM2 B-frags (prefetch early; L2-resident Wt)
        const short* wg = Wt + (size_t)g*4096;
        short8 bw[2][4];
        #pragma unroll
        for (int kt = 0; kt < 2; ++kt)
            #pragma unroll
            for (int nt = 0; nt < 4; ++nt)
                bw[kt][nt] = *(const short8*)(wg + (nt*16 + ln15)*64 + kt*32 + ln4*8);

        // S-frags: S[i][j] = (cm==g) as bf16 1.0/0.0
        short8 sf[2];
        #pragma unroll
        for (int kt = 0; kt < 2; ++kt)
            #pragma unroll
            for (int u = 0; u < 8; ++u) {
                unsigned byte = ((u < 4 ? cmv[kt][0] >> (8*u) : cmv[kt][1] >> (8*(u-4))) & 255u);
                sf[kt][u] = (byte == (unsigned)g) ? (short)0x3F80 : (short)0;
            }
        // GEMM1: P (rows w*16..w*16+15) = S @ H, f32 accumulate
        f32x4 pt[4];
        #pragma unroll
        for (int nt = 0; nt < 4; ++nt) pt[nt] = (f32x4){0.f,0.f,0.f,0.f};
        #pragma unroll
        for (int kt = 0; kt < 2; ++kt)
            #pragma unroll
            for (int nt = 0; nt < 4; ++nt)
                pt[nt] = __builtin_amdgcn_mfma_f32_16x16x32_bf16(sf[kt], hf[kt][nt], pt[nt], 0, 0, 0);
        // roundtrip: C-layout -> bf16 LDS (wave-disjoint rows; lgkmcnt only, no barrier)
        #pragma unroll
        for (int nt = 0; nt < 4; ++nt)
            #pragma unroll
            for (int r = 0; r < 4; ++r)
                Pw[(w*16 + ln4*4 + r)*72 + nt*16 + ln15] = f2b(pt[nt][r]);
        short8 af0 = *(const short8*)(Pw + (w*16 + ln15)*72 + ln4*8);
        short8 af1 = *(const short8*)(Pw + (w*16 + ln15)*72 + 32 + ln4*8);
        // GEMM2: X += P @ W_g
        #pragma unroll
        for (int nt = 0; nt < 4; ++nt) {
            acc[nt] = __builtin_amdgcn_mfma_f32_16x16x32_bf16(af0, bw[0][nt], acc[nt], 0, 0, 0);
            acc[nt] = __builtin_amdgcn_mfma_f32_16x16x32_bf16(af1, bw[1][nt], acc[nt], 0, 0, 0);
        }
    }

    // epilogue: wave w owns X rows w*16..w*16+15. Write X+bias, column stats.
    #pragma unroll
    for (int nt = 0; nt < 4; ++nt) {
        const int col = nt*16 + ln15;
        float s1 = 0.f, s2 = 0.f;
        #pragma unroll
        for (int r = 0; r < 4; ++r) {
            float xv = acc[nt][r] + bcol[nt];
            X[(size_t)(base + w*16 + ln4*4 + r)*64 + col] = xv;
            s1 += xv; s2 += xv*xv;
        }
        // reduce over ln4 (lanes col-equal differ in bits 4,5)
        s1 += __shfl_xor(s1, 16); s1 += __shfl_xor(s1, 32);
        s2 += __shfl_xor(s2, 16); s2 += __shfl_xor(s2, 32);
        if (ln4 == 0) { red1[w*64 + col] = s1; red2[w*64 + col] = s2; }
    }
    __syncthreads();
    if (tid < 128) {
        int half = tid >> 6, c = tid & 63;
        const float* r0 = half ? red2 : red1;
        float v = r0[c] + r0[64 + c] + r0[128 + c] + r0[192 + c];
        partials[(size_t)b*128 + half*64 + c] = v;          // [block][slot]
    }
}

// ---------------- K2: redundant stats reduce + normalize + ReLU ----------------
__global__ __launch_bounds__(256) void sp_finish(
    float* __restrict__ X, const float* __restrict__ partials,
    const float* __restrict__ gamma, const float* __restrict__ beta)
{
    __shared__ float sp0[128], sp1[128];                    // two halves of block-range
    __shared__ float scale[64], shift[64];
    const int b = blockIdx.x, tid = threadIdx.x;

    {   // all 256 threads: slot = tid&127, half-range = tid>>7
        const int slot = tid & 127, hb = tid >> 7;
        float v = 0.f;
        const float* p = partials + (size_t)hb*128*128 + slot;
        #pragma unroll 4
        for (int bb = 0; bb < 128; ++bb) v += p[(size_t)bb*128];
        (hb ? sp1 : sp0)[slot] = v;
    }
    __syncthreads();
    if (tid < 64) {
        const float inv_n = 1.0f / (float)NTOT;
        float s1 = sp0[tid] + sp1[tid];
        float s2 = sp0[64 + tid] + sp1[64 + tid];
        float mu  = s1 * inv_n;
        float var = s2 * inv_n - mu*mu;
        float sc  = gamma[tid] / sqrtf(var + EPSV);
        scale[tid] = sc;
        shift[tid] = beta[tid] - mu*sc;
    }
    __syncthreads();
    // normalize 4096 floats: X[b*4096 .. +4096)
    #pragma unroll
    for (int q = 0; q < 4; ++q) {
        size_t idx4 = (size_t)b*1024 + q*256 + tid;         // f32x4 units
        f32x4 v = ((f32x4*)X)[idx4];
        int c0 = ((int)idx4*4) & 63;
        #pragma unroll
        for (int u = 0; u < 4; ++u)
            v[u] = fmaxf(v[u]*scale[c0 + u] + shift[c0 + u], 0.0f);
        ((f32x4*)X)[idx4] = v;
    }
}

extern "C" void kernel_launch(void* const* d_in, const int* in_sizes, int n_in,
                              void* d_out, int out_size, void* d_ws, size_t ws_size,
                              hipStream_t stream)
{
    const float* h     = (const float*)d_in[0];
    // d_in[1] seq_start_end: provably uniform (reference only uses N//nseq)
    const float* pos   = (const float*)d_in[2];
    const float* W     = (const float*)d_in[3];
    const float* bvec  = (const float*)d_in[4];
    const float* gamma = (const float*)d_in[5];
    const float* beta  = (const float*)d_in[6];

    float* X        = (float*)d_out;
    short* Wt       = (short*)d_ws;                         // 512 KB bf16 W^T
    float* partials = (float*)((char*)d_ws + 524288);       // 256*128*4 = 128 KB

    sp_transpose<<<64,   256, 0, stream>>>(W, Wt);
    sp_main     <<<NSEQ, 256, 0, stream>>>(h, pos, Wt, bvec, X, partials);
    sp_finish   <<<NSEQ, 256, 0, stream>>>(X, partials, gamma, beta);
}